// Round 1
// baseline (368.805 us; speedup 1.0000x reference)
//
#include <hip/hip_runtime.h>

// MovingAverageLayer: x (T=262144, F=64) fp32 -> out (T, 4F) fp32
// out[:, 0:64]    = x
// out[:, 64:128]  = ma7   (windowed for i>=6, expanding mean for i<6)
// out[:, 128:192] = ma30
// out[:, 192:256] = ma90
//
// Sliding-window scan: one thread per (chunk, column). 64 threads cover one
// chunk's 64 columns -> every global load/store is a coalesced 256B wave
// transaction. Running sums updated as s += x[i] - x[i-p]; re-reads of the
// trailing window (<= 90 rows * 256B = 23KB per wave) are L1/L2 hits.

#define T_ROWS 262144
#define F_COLS 64
#define OUT_COLS 256
#define CHUNK 128                 // rows per chunk; must be > 90 and divide T_ROWS
#define CHUNKS_PER_BLOCK 4        // 256-thread blocks, one wave per chunk

__global__ __launch_bounds__(256) void ma_kernel(const float* __restrict__ x,
                                                 float* __restrict__ out) {
    const int tid   = threadIdx.x;
    const int col   = tid & 63;                                  // column 0..63
    const int chunk = blockIdx.x * CHUNKS_PER_BLOCK + (tid >> 6); // wave-uniform
    const long r0   = (long)chunk * CHUNK;

    const float* __restrict__ xc = x + col;     // stride F_COLS per row
    float* __restrict__ oc = out + col;         // stride OUT_COLS per row

    float s7 = 0.f, s30 = 0.f, s90 = 0.f;

    if (chunk == 0) {
        // Guarded path: rows 0..CHUNK-1 include the expanding-mean region.
        for (int i = 0; i < CHUNK; ++i) {
            float v = xc[(long)i * F_COLS];
            s7 += v; s30 += v; s90 += v;
            if (i >= 7)  s7  -= xc[(long)(i - 7)  * F_COLS];
            if (i >= 30) s30 -= xc[(long)(i - 30) * F_COLS];
            if (i >= 90) s90 -= xc[(long)(i - 90) * F_COLS];
            float d7  = (i < 6)  ? (float)(i + 1) : 7.f;
            float d30 = (i < 29) ? (float)(i + 1) : 30.f;
            float d90 = (i < 89) ? (float)(i + 1) : 90.f;
            long ob = (long)i * OUT_COLS;
            oc[ob]       = v;
            oc[ob + 64]  = s7  / d7;
            oc[ob + 128] = s30 / d30;
            oc[ob + 192] = s90 / d90;
        }
    } else {
        // Warm-up: seed the three window sums from the 90 rows before r0.
        // (r0 >= CHUNK > 90, so all indices are in range and windows full.)
        #pragma unroll
        for (int k = 1; k <= 7; ++k) {
            float v = xc[(r0 - k) * F_COLS];
            s7 += v; s30 += v; s90 += v;
        }
        #pragma unroll
        for (int k = 8; k <= 30; ++k) {
            float v = xc[(r0 - k) * F_COLS];
            s30 += v; s90 += v;
        }
        #pragma unroll 2
        for (int k = 31; k <= 90; ++k) {
            s90 += xc[(r0 - k) * F_COLS];
        }

        const float r7 = 1.f / 7.f, r30 = 1.f / 30.f, r90 = 1.f / 90.f;
        #pragma unroll 4
        for (int i = 0; i < CHUNK; ++i) {
            const long gi = r0 + i;
            float v   = xc[gi * F_COLS];
            float o7  = xc[(gi - 7)  * F_COLS];
            float o30 = xc[(gi - 30) * F_COLS];
            float o90 = xc[(gi - 90) * F_COLS];
            s7  += v - o7;
            s30 += v - o30;
            s90 += v - o90;
            const long ob = gi * OUT_COLS;
            oc[ob]       = v;
            oc[ob + 64]  = s7  * r7;
            oc[ob + 128] = s30 * r30;
            oc[ob + 192] = s90 * r90;
        }
    }
}

extern "C" void kernel_launch(void* const* d_in, const int* in_sizes, int n_in,
                              void* d_out, int out_size, void* d_ws, size_t ws_size,
                              hipStream_t stream) {
    const float* x = (const float*)d_in[0];
    float* out = (float*)d_out;
    const int n_chunks = T_ROWS / CHUNK;                 // 2048
    const int n_blocks = n_chunks / CHUNKS_PER_BLOCK;    // 512
    ma_kernel<<<n_blocks, 256, 0, stream>>>(x, out);
}